// Round 7
// baseline (327.458 us; speedup 1.0000x reference)
//
#include <hip/hip_runtime.h>
#include <hip/hip_bf16.h>
#include <stdint.h>

#define B_   4
#define C_   768
#define T_   2048
#define H_   12
#define D_   64
#define O3_  2304

typedef __attribute__((ext_vector_type(4))) float f32x4;
typedef __attribute__((ext_vector_type(8))) short bf16x8;
typedef __attribute__((ext_vector_type(4))) _Float16 f16x4;
typedef __attribute__((ext_vector_type(2))) __fp16 h16x2;

__device__ __forceinline__ unsigned short f2bf(float f) {
  union { float f; unsigned int u; } v; v.f = f;
  unsigned int r = v.u + 0x7fffu + ((v.u >> 16) & 1u);
  return (unsigned short)(r >> 16);
}

__device__ __forceinline__ unsigned short f2h(float f) {
  union { _Float16 h; unsigned short u; } c; c.h = (_Float16)f; return c.u;
}

__device__ __forceinline__ float h2f(unsigned short u) {
  union { _Float16 h; unsigned short u; } c; c.u = u; return (float)c.h;
}

__device__ __forceinline__ float fexp2(float x) {
#if __has_builtin(__builtin_amdgcn_exp2f)
  return __builtin_amdgcn_exp2f(x);
#else
  return exp2f(x);
#endif
}

// async global->LDS, 16B per lane; LDS dest = wave-uniform base + lane*16.
__device__ __forceinline__ void async16(const void* g, void* lds) {
#if __has_builtin(__builtin_amdgcn_global_load_lds)
  __builtin_amdgcn_global_load_lds((const __attribute__((address_space(1))) void*)g,
                                   (__attribute__((address_space(3))) void*)lds, 16, 0, 0);
#else
  int lane = threadIdx.x & 63;
  *((uint4*)((char*)lds + lane * 16)) = *((const uint4*)g);
#endif
}

// ---------------------------------------------------------------- prep kernels

__global__ void cvt_f32_bf16(const float* __restrict__ in,
                             unsigned short* __restrict__ out, int n4) {
  int i = blockIdx.x * 256 + threadIdx.x;
  if (i < n4) {
    float4 f = ((const float4*)in)[i];
    ushort4 o;
    o.x = f2bf(f.x); o.y = f2bf(f.y); o.z = f2bf(f.z); o.w = f2bf(f.w);
    ((ushort4*)out)[i] = o;
  }
}

// mask (B,1,1,T) int -> additive bias in exp2 domain
__global__ void make_bias(const int* __restrict__ mask, float* __restrict__ mbias, int n) {
  int i = blockIdx.x * 256 + threadIdx.x;
  if (i < n) mbias[i] = (mask[i] == 0) ? -14426.950408f : 0.0f;
}

// x[b][c][t] fp32 -> xT[b][t][c] bf16
__global__ void transpose_x(const float* __restrict__ x,
                            unsigned short* __restrict__ xT) {
  __shared__ unsigned short tile[32][33];
  int b = blockIdx.z;
  int c0 = blockIdx.y * 32;
  int t0 = blockIdx.x * 32;
  int tid = threadIdx.x;
  {
    int cl = tid >> 3;
    int tl = (tid & 7) * 4;
    float4 f = *(const float4*)(x + ((size_t)b * C_ + c0 + cl) * T_ + t0 + tl);
    tile[tl + 0][cl] = f2bf(f.x);
    tile[tl + 1][cl] = f2bf(f.y);
    tile[tl + 2][cl] = f2bf(f.z);
    tile[tl + 3][cl] = f2bf(f.w);
  }
  __syncthreads();
  {
    int tl = tid >> 3;
    int cl = (tid & 7) * 4;
    ushort4 o;
    o.x = tile[tl][cl + 0]; o.y = tile[tl][cl + 1];
    o.z = tile[tl][cl + 2]; o.w = tile[tl][cl + 3];
    *(ushort4*)(xT + ((size_t)b * T_ + t0 + tl) * C_ + c0 + cl) = o;
  }
}

// ---------------------------------------------------------------- QKV GEMM
// Epilogue layouts for attn:
//   Qb[bh][t][dd]  bf16               (prescaled by 0.125*log2e)
//   Kb[bh][s][dd]  bf16  rows 64 shorts, 16B chunk c=dd>>3 stored at c^(s&7)
//   Vb[bh][tile][dd][64] f16  64-s tiles, chunk c=si>>3 stored at c^(dd&7)
__global__ __launch_bounds__(256)
void gemm_qkv(const unsigned short* __restrict__ xT,
              const unsigned short* __restrict__ W1,
              const float* __restrict__ bqkv,
              unsigned short* __restrict__ Qb,
              unsigned short* __restrict__ Kb,
              unsigned short* __restrict__ Vb) {
  __shared__ unsigned short sA[2][128 * 32];
  __shared__ unsigned short sB[2][128 * 32];

  const int b   = blockIdx.z;
  const int o0  = blockIdx.y * 128;
  const int t0  = blockIdx.x * 128;
  const int tid = threadIdx.x;
  const int wave = tid >> 6, lane = tid & 63;
  const int q = lane >> 4, ln = lane & 15;
  const int tw = wave >> 1, ow = wave & 1;

  const unsigned short* Ax = xT + (size_t)b * T_ * C_;
  const int srow = lane >> 2;
  const int scol = (lane & 3) * 8;

  const f32x4 ZERO = {0.f, 0.f, 0.f, 0.f};
  f32x4 acc[4][4];
#pragma unroll
  for (int mi = 0; mi < 4; ++mi)
#pragma unroll
    for (int ni = 0; ni < 4; ++ni) acc[mi][ni] = ZERO;

#pragma unroll
  for (int j = 0; j < 2; ++j) {
    const int chunk = wave * 2 + j;
    const int row = chunk * 16 + srow;
    async16(Ax + (size_t)(t0 + row) * C_ + scol, &sA[0][chunk * 512]);
    async16(W1 + (size_t)(o0 + row) * C_ + scol, &sB[0][chunk * 512]);
  }

  for (int i = 0; i < 24; ++i) {
    const int buf = i & 1;
    __syncthreads();
    if (i < 23) {
      const int k0 = (i + 1) * 32;
#pragma unroll
      for (int j = 0; j < 2; ++j) {
        const int chunk = wave * 2 + j;
        const int row = chunk * 16 + srow;
        async16(Ax + (size_t)(t0 + row) * C_ + k0 + scol, &sA[buf ^ 1][chunk * 512]);
        async16(W1 + (size_t)(o0 + row) * C_ + k0 + scol, &sB[buf ^ 1][chunk * 512]);
      }
    }

    bf16x8 aF[4], bF[4];
#pragma unroll
    for (int mi = 0; mi < 4; ++mi)
      aF[mi] = *(const bf16x8*)(&sA[buf][(tw * 64 + mi * 16 + ln) * 32 + q * 8]);
#pragma unroll
    for (int ni = 0; ni < 4; ++ni)
      bF[ni] = *(const bf16x8*)(&sB[buf][(ow * 64 + ni * 16 + ln) * 32 + q * 8]);
#pragma unroll
    for (int mi = 0; mi < 4; ++mi)
#pragma unroll
      for (int ni = 0; ni < 4; ++ni)
        acc[mi][ni] = __builtin_amdgcn_mfma_f32_16x16x32_bf16(aF[mi], bF[ni], acc[mi][ni], 0, 0, 0);
  }

  const float QSCL = 0.125f * 1.44269504f;
#pragma unroll
  for (int ni = 0; ni < 4; ++ni) {
    const int o = o0 + ow * 64 + ni * 16 + ln;
    const float bias = bqkv[o];
    const int which = o / C_;          // uniform per block (768 % 128 == 0)
    const int rem = o - which * C_;
    const int bh = b * H_ + (rem >> 6);
    const int dd = rem & 63;
#pragma unroll
    for (int mi = 0; mi < 4; ++mi) {
      const int tb = t0 + tw * 64 + mi * 16 + q * 4;
      f32x4 v = acc[mi][ni];
      if (which == 0) {
#pragma unroll
        for (int r = 0; r < 4; ++r)
          Qb[((size_t)bh * T_ + tb + r) * D_ + dd] = f2bf((v[r] + bias) * QSCL);
      } else if (which == 1) {
#pragma unroll
        for (int r = 0; r < 4; ++r) {
          const int s = tb + r;
          const int cp = (dd >> 3) ^ (s & 7);
          Kb[((size_t)bh * T_ + s) * 64 + (cp << 3) + (dd & 7)] = f2bf(v[r] + bias);
        }
      } else {
        const int tile = tb >> 6, si = tb & 63;
        const int cp = (si >> 3) ^ (dd & 7);
        ushort4 pk;                      // V stored as f16 for the f16 PV MFMA
        pk.x = f2h(v[0] + bias);
        pk.y = f2h(v[1] + bias);
        pk.z = f2h(v[2] + bias);
        pk.w = f2h(v[3] + bias);
        *(ushort4*)(Vb + (((size_t)bh * 32 + tile) * 64 + dd) * 64 + (cp << 3) + (si & 7)) = pk;
      }
    }
  }
}

// ---------------------------------------------------------------- attention
// Fixed-max flash. One block = (bh, 64 t); 4 waves each own ALL 64 t x a 16-s
// slice of the 64-s tile. P stays in REGISTERS: QK^T C-layout (s=4q+r,t=ln)
// == A-layout of 16x16x16 MFMA (k=4q+j,m=ln), so PV needs no LDS round-trip.
// l = per-lane VALU sums. Cross-wave combine once at the end via LDS (f16).
__global__ __launch_bounds__(256, 4)
void attn(const unsigned short* __restrict__ Qb,
          const unsigned short* __restrict__ Kb,
          const unsigned short* __restrict__ Vb,
          const float* __restrict__ mbias,
          unsigned short* __restrict__ Ob) {
  __shared__ __align__(16) char smem[32768];
  unsigned short* sK0 = (unsigned short*)smem;             // dbuf 2 x 8KB
  unsigned short* sV0 = (unsigned short*)(smem + 16384);   // dbuf 2 x 8KB

  const int id = blockIdx.x;                  // id = bh + 48*tblk -> XCD = bh%8
  const int bh = id % 48;
  const int tblk = id / 48;                   // 0..31, 64 t each
  const int b = bh / H_, h = bh % H_;
  const int tid = threadIdx.x, si = tid >> 6, lane = tid & 63;
  const int q = lane >> 4, ln = lane & 15;
  const int t0 = tblk * 64;

  // Q fragments (B-operand of QK): [tt][kk], t = t0 + tt*16 + ln
  bf16x8 Qa[4][2];
#pragma unroll
  for (int tt = 0; tt < 4; ++tt) {
    const unsigned short* qrow = Qb + ((size_t)bh * T_ + t0 + tt * 16 + ln) * D_;
    Qa[tt][0] = *(const bf16x8*)(qrow + q * 8);
    Qa[tt][1] = *(const bf16x8*)(qrow + 32 + q * 8);
  }

  const f32x4 ZERO = {0.f, 0.f, 0.f, 0.f};
  f32x4 Oacc[4][4];            // [tt][dt]: O[t][d] C-layout (row t, col d)
  float lac[4] = {0.f, 0.f, 0.f, 0.f};
#pragma unroll
  for (int tt = 0; tt < 4; ++tt)
#pragma unroll
    for (int dt = 0; dt < 4; ++dt) Oacc[tt][dt] = ZERO;

  const unsigned short* gK = Kb + (size_t)bh * T_ * 64;
  const unsigned short* gV = Vb + (size_t)bh * 32 * 4096;

  // prologue: stage iter 0 into buf 0 (K,V: 8 chunks of 1KB, 2 per wave)
#pragma unroll
  for (int j = 0; j < 2; ++j) {
    const int chunk = si * 2 + j;
    async16(gK + chunk * 512 + lane * 8, sK0 + chunk * 512);
    async16(gV + chunk * 512 + lane * 8, sV0 + chunk * 512);
  }

  for (int it = 0; it < 32; ++it) {
    const int buf = it & 1;
    __syncthreads();                    // vmcnt drain: buf ready & visible
    if (it < 31) {
      const unsigned short* k = gK + (it + 1) * 4096;
      const unsigned short* v = gV + (it + 1) * 4096;
      unsigned short* dK = sK0 + (buf ^ 1) * 4096;
      unsigned short* dV = sV0 + (buf ^ 1) * 4096;
#pragma unroll
      for (int j = 0; j < 2; ++j) {
        const int chunk = si * 2 + j;
        async16(k + chunk * 512 + lane * 8, dK + chunk * 512);
        async16(v + chunk * 512 + lane * 8, dV + chunk * 512);
      }
    }

    const int s0 = it * 64;
    const float bvl = mbias[b * T_ + s0 + lane];
    const bool anymask = (__ballot(bvl != 0.0f) != 0ull);
    const unsigned short* sKc = sK0 + buf * 4096;
    const unsigned short* sVc = sV0 + buf * 4096;

    // K A-fragments for this wave's 16-s slice (row = si*16 + ln)
    const unsigned short* krow = sKc + (si * 16 + ln) * 64;
    bf16x8 kf0 = *(const bf16x8*)(krow + ((q ^ (ln & 7)) << 3));
    bf16x8 kf1 = *(const bf16x8*)(krow + (((4 + q) ^ (ln & 7)) << 3));

    f32x4 bb = ZERO;
    if (anymask) bb = *(const f32x4*)(mbias + b * T_ + s0 + si * 16 + q * 4);

    // QK^T -> p = exp2(sc) -> P stays in registers as f16 A-frags
    f16x4 Pf[4];
#pragma unroll
    for (int tt = 0; tt < 4; ++tt) {
      f32x4 p0 = __builtin_amdgcn_mfma_f32_16x16x32_bf16(kf0, Qa[tt][0], ZERO, 0, 0, 0);
      f32x4 sc = __builtin_amdgcn_mfma_f32_16x16x32_bf16(kf1, Qa[tt][1], p0, 0, 0, 0);
      if (anymask) {
#pragma unroll
        for (int r = 0; r < 4; ++r) sc[r] += bb[r];
      }
      float e0 = fexp2(sc[0]), e1 = fexp2(sc[1]);
      float e2 = fexp2(sc[2]), e3 = fexp2(sc[3]);
      lac[tt] += (e0 + e1) + (e2 + e3);
      union { h16x2 h2[2]; f16x4 h4; } u;
      u.h2[0] = __builtin_amdgcn_cvt_pkrtz(e0, e1);
      u.h2[1] = __builtin_amdgcn_cvt_pkrtz(e2, e3);
      Pf[tt] = u.h4;
    }

    // PV: O[t][d] += P (A, registers) x V (B, f16 b64 LDS reads)
#pragma unroll
    for (int dt = 0; dt < 4; ++dt) {
      f16x4 vf = *(const f16x4*)(sVc + (dt * 16 + ln) * 64 +
                                 (((si * 2 + (q >> 1)) ^ (ln & 7)) << 3) + ((q & 1) << 2));
#pragma unroll
      for (int tt = 0; tt < 4; ++tt)
        Oacc[tt][dt] = __builtin_amdgcn_mfma_f32_16x16x16f16(Pf[tt], vf, Oacc[tt][dt], 0, 0, 0);
    }
  }

  // reduce l over the 4 quads (lanes sharing ln hold same t)
#pragma unroll
  for (int tt = 0; tt < 4; ++tt) {
    lac[tt] += __shfl_xor(lac[tt], 16, 64);
    lac[tt] += __shfl_xor(lac[tt], 32, 64);
  }

  // ---- cross-wave combine (si=1..3 -> LDS f16 partials; si=0 merges)
  __syncthreads();
  unsigned short* hbuf = (unsigned short*)smem;       // 3 x [64t][64d] f16
  float* lbuf = (float*)(smem + 24576);               // 3 x [64t] f32
  if (si > 0) {
    const int base = (si - 1) * 4096;
#pragma unroll
    for (int tt = 0; tt < 4; ++tt) {
#pragma unroll
      for (int dt = 0; dt < 4; ++dt)
#pragma unroll
        for (int r = 0; r < 4; ++r)
          hbuf[base + (tt * 16 + q * 4 + r) * 64 + dt * 16 + ln] = f2h(Oacc[tt][dt][r]);
      if (q == 0) lbuf[(si - 1) * 64 + tt * 16 + ln] = lac[tt];
    }
  }
  __syncthreads();
  if (si == 0) {
#pragma unroll
    for (int tt = 0; tt < 4; ++tt) {
      float inv[4];
#pragma unroll
      for (int r = 0; r < 4; ++r) {
        const int tl = tt * 16 + q * 4 + r;
        float l = __shfl(lac[tt], q * 4 + r, 64);   // lane (0, 4q+r) holds t=tl
        l += lbuf[tl] + lbuf[64 + tl] + lbuf[128 + tl];
        inv[r] = 1.0f / l;
      }
#pragma unroll
      for (int dt = 0; dt < 4; ++dt) {
#pragma unroll
        for (int r = 0; r < 4; ++r) {
          const int tl = tt * 16 + q * 4 + r;
          const int dl = dt * 16 + ln;
          float o = Oacc[tt][dt][r]
                  + h2f(hbuf[tl * 64 + dl])
                  + h2f(hbuf[4096 + tl * 64 + dl])
                  + h2f(hbuf[8192 + tl * 64 + dl]);
          Ob[((size_t)b * T_ + t0 + tl) * C_ + h * D_ + dl] = f2bf(o * inv[r]);
        }
      }
    }
  }
}

// ---------------------------------------------------------------- out GEMM
__global__ __launch_bounds__(256)
void gemm_out(const unsigned short* __restrict__ Ob,
              const unsigned short* __restrict__ W2,
              const float* __restrict__ bout,
              float* __restrict__ out) {
  __shared__ unsigned short sA[2][128 * 32];
  __shared__ unsigned short sB[2][128 * 32];

  const int b   = blockIdx.z;
  const int o0  = blockIdx.y * 128;
  const int t0  = blockIdx.x * 128;
  const int tid = threadIdx.x;
  const int wave = tid >> 6, lane = tid & 63;
  const int q = lane >> 4, ln = lane & 15;
  const int tw = wave >> 1, ow = wave & 1;

  const unsigned short* Bo = Ob + (size_t)b * T_ * C_;
  const int srow = lane >> 2;
  const int scol = (lane & 3) * 8;

  const f32x4 ZERO = {0.f, 0.f, 0.f, 0.f};
  f32x4 acc[4][4];
#pragma unroll
  for (int mi = 0; mi < 4; ++mi)
#pragma unroll
    for (int ni = 0; ni < 4; ++ni) acc[mi][ni] = ZERO;

#pragma unroll
  for (int j = 0; j < 2; ++j) {
    const int chunk = wave * 2 + j;
    const int row = chunk * 16 + srow;
    async16(W2 + (size_t)(o0 + row) * C_ + scol, &sA[0][chunk * 512]);
    async16(Bo + (size_t)(t0 + row) * C_ + scol, &sB[0][chunk * 512]);
  }

  for (int i = 0; i < 24; ++i) {
    const int buf = i & 1;
    __syncthreads();
    if (i < 23) {
      const int k0 = (i + 1) * 32;
#pragma unroll
      for (int j = 0; j < 2; ++j) {
        const int chunk = wave * 2 + j;
        const int row = chunk * 16 + srow;
        async16(W2 + (size_t)(o0 + row) * C_ + k0 + scol, &sA[buf ^ 1][chunk * 512]);
        async16(Bo + (size_t)(t0 + row) * C_ + k0 + scol, &sB[buf ^ 1][chunk * 512]);
      }
    }

    bf16x8 aF[4], bF[4];
#pragma unroll
    for (int mi = 0; mi < 4; ++mi)
      aF[mi] = *(const bf16x8*)(&sA[buf][(tw * 64 + mi * 16 + ln) * 32 + q * 8]);
#pragma unroll
    for (int ni = 0; ni < 4; ++ni)
      bF[ni] = *(const bf16x8*)(&sB[buf][(ow * 64 + ni * 16 + ln) * 32 + q * 8]);
#pragma unroll
    for (int mi = 0; mi < 4; ++mi)
#pragma unroll
      for (int ni = 0; ni < 4; ++ni)
        acc[mi][ni] = __builtin_amdgcn_mfma_f32_16x16x32_bf16(aF[mi], bF[ni], acc[mi][ni], 0, 0, 0);
  }

#pragma unroll
  for (int mi = 0; mi < 4; ++mi) {
    const int ob = o0 + tw * 64 + mi * 16 + q * 4;
#pragma unroll
    for (int ni = 0; ni < 4; ++ni) {
      const int t = t0 + ow * 64 + ni * 16 + ln;
      f32x4 v = acc[mi][ni];
#pragma unroll
      for (int r = 0; r < 4; ++r)
        out[((size_t)b * C_ + ob + r) * T_ + t] = v[r] + bout[ob + r];
    }
  }
}

// ---------------------------------------------------------------- launch

extern "C" void kernel_launch(void* const* d_in, const int* in_sizes, int n_in,
                              void* d_out, int out_size, void* d_ws, size_t ws_size,
                              hipStream_t stream) {
  (void)in_sizes; (void)n_in; (void)out_size; (void)ws_size;
  const float* x    = (const float*)d_in[0];
  const int*   mask = (const int*)d_in[1];
  const float* Wqkv = (const float*)d_in[2];
  const float* bqkv = (const float*)d_in[3];
  const float* Wout = (const float*)d_in[4];
  const float* bout = (const float*)d_in[5];
  float* out = (float*)d_out;

  const size_t szHead = (size_t)B_ * H_ * T_ * D_;   // 6291456 elems
  const size_t szBTC  = (size_t)B_ * T_ * C_;        // 6291456 elems
  unsigned short* Qb  = (unsigned short*)d_ws;
  unsigned short* Kb  = Qb + szHead;
  unsigned short* Vb  = Kb + szHead;
  unsigned short* Ob  = Vb + szHead;
  unsigned short* xT  = Ob + szBTC;
  unsigned short* W1b = xT + szBTC;
  unsigned short* W2b = W1b + (size_t)O3_ * C_;
  float* mbias        = (float*)(W2b + (size_t)C_ * C_);

  cvt_f32_bf16<<<dim3((O3_ * C_ / 4 + 255) / 256), 256, 0, stream>>>(Wqkv, W1b, O3_ * C_ / 4);
  cvt_f32_bf16<<<dim3((C_ * C_ / 4 + 255) / 256), 256, 0, stream>>>(Wout, W2b, C_ * C_ / 4);
  make_bias<<<dim3((B_ * T_ + 255) / 256), 256, 0, stream>>>(mask, mbias, B_ * T_);
  transpose_x<<<dim3(T_ / 32, C_ / 32, B_), 256, 0, stream>>>(x, xT);
  gemm_qkv<<<dim3(T_ / 128, O3_ / 128, B_), 256, 0, stream>>>(xT, W1b, bqkv, Qb, Kb, Vb);
  attn<<<dim3(1536), 256, 0, stream>>>(Qb, Kb, Vb, mbias, Ob);
  gemm_out<<<dim3(T_ / 128, C_ / 128, B_), 256, 0, stream>>>(Ob, W2b, bout, out);
}

// Round 8
// 243.616 us; speedup vs baseline: 1.3442x; 1.3442x over previous
//
#include <hip/hip_runtime.h>
#include <hip/hip_bf16.h>
#include <stdint.h>

#define B_   4
#define C_   768
#define T_   2048
#define H_   12
#define D_   64
#define O3_  2304

typedef __attribute__((ext_vector_type(4))) float f32x4;
typedef __attribute__((ext_vector_type(8))) short bf16x8;
typedef __attribute__((ext_vector_type(4))) _Float16 f16x4;
typedef __attribute__((ext_vector_type(2))) __fp16 h16x2;

__device__ __forceinline__ unsigned short f2bf(float f) {
  union { float f; unsigned int u; } v; v.f = f;
  unsigned int r = v.u + 0x7fffu + ((v.u >> 16) & 1u);
  return (unsigned short)(r >> 16);
}

__device__ __forceinline__ unsigned short f2h(float f) {
  union { _Float16 h; unsigned short u; } c; c.h = (_Float16)f; return c.u;
}

__device__ __forceinline__ float h2f(unsigned short u) {
  union { _Float16 h; unsigned short u; } c; c.u = u; return (float)c.h;
}

__device__ __forceinline__ float fexp2(float x) {
#if __has_builtin(__builtin_amdgcn_exp2f)
  return __builtin_amdgcn_exp2f(x);
#else
  return exp2f(x);
#endif
}

// async global->LDS, 16B per lane; LDS dest = wave-uniform base + lane*16.
__device__ __forceinline__ void async16(const void* g, void* lds) {
#if __has_builtin(__builtin_amdgcn_global_load_lds)
  __builtin_amdgcn_global_load_lds((const __attribute__((address_space(1))) void*)g,
                                   (__attribute__((address_space(3))) void*)lds, 16, 0, 0);
#else
  int lane = threadIdx.x & 63;
  *((uint4*)((char*)lds + lane * 16)) = *((const uint4*)g);
#endif
}

// ---------------------------------------------------------------- prep kernels

__global__ void cvt_f32_bf16(const float* __restrict__ in,
                             unsigned short* __restrict__ out, int n4) {
  int i = blockIdx.x * 256 + threadIdx.x;
  if (i < n4) {
    float4 f = ((const float4*)in)[i];
    ushort4 o;
    o.x = f2bf(f.x); o.y = f2bf(f.y); o.z = f2bf(f.z); o.w = f2bf(f.w);
    ((ushort4*)out)[i] = o;
  }
}

// mask (B,1,1,T) int -> additive bias in exp2 domain
__global__ void make_bias(const int* __restrict__ mask, float* __restrict__ mbias, int n) {
  int i = blockIdx.x * 256 + threadIdx.x;
  if (i < n) mbias[i] = (mask[i] == 0) ? -14426.950408f : 0.0f;
}

// x[b][c][t] fp32 -> xT[b][t][c] bf16
__global__ void transpose_x(const float* __restrict__ x,
                            unsigned short* __restrict__ xT) {
  __shared__ unsigned short tile[32][33];
  int b = blockIdx.z;
  int c0 = blockIdx.y * 32;
  int t0 = blockIdx.x * 32;
  int tid = threadIdx.x;
  {
    int cl = tid >> 3;
    int tl = (tid & 7) * 4;
    float4 f = *(const float4*)(x + ((size_t)b * C_ + c0 + cl) * T_ + t0 + tl);
    tile[tl + 0][cl] = f2bf(f.x);
    tile[tl + 1][cl] = f2bf(f.y);
    tile[tl + 2][cl] = f2bf(f.z);
    tile[tl + 3][cl] = f2bf(f.w);
  }
  __syncthreads();
  {
    int tl = tid >> 3;
    int cl = (tid & 7) * 4;
    ushort4 o;
    o.x = tile[tl][cl + 0]; o.y = tile[tl][cl + 1];
    o.z = tile[tl][cl + 2]; o.w = tile[tl][cl + 3];
    *(ushort4*)(xT + ((size_t)b * T_ + t0 + tl) * C_ + c0 + cl) = o;
  }
}

// ---------------------------------------------------------------- QKV GEMM
// Epilogue layouts for attn:
//   Qb[bh][t][dd]  bf16               (prescaled by 0.125*log2e)
//   Kb[bh][s][dd]  bf16  rows 64 shorts, 16B chunk c=dd>>3 stored at c^(s&7)
//   Vb[bh][tile][dd][64] f16  64-s tiles, chunk c=si>>3 stored at c^(dd&7)
__global__ __launch_bounds__(256)
void gemm_qkv(const unsigned short* __restrict__ xT,
              const unsigned short* __restrict__ W1,
              const float* __restrict__ bqkv,
              unsigned short* __restrict__ Qb,
              unsigned short* __restrict__ Kb,
              unsigned short* __restrict__ Vb) {
  __shared__ unsigned short sA[2][128 * 32];
  __shared__ unsigned short sB[2][128 * 32];

  const int b   = blockIdx.z;
  const int o0  = blockIdx.y * 128;
  const int t0  = blockIdx.x * 128;
  const int tid = threadIdx.x;
  const int wave = tid >> 6, lane = tid & 63;
  const int q = lane >> 4, ln = lane & 15;
  const int tw = wave >> 1, ow = wave & 1;

  const unsigned short* Ax = xT + (size_t)b * T_ * C_;
  const int srow = lane >> 2;
  const int scol = (lane & 3) * 8;

  const f32x4 ZERO = {0.f, 0.f, 0.f, 0.f};
  f32x4 acc[4][4];
#pragma unroll
  for (int mi = 0; mi < 4; ++mi)
#pragma unroll
    for (int ni = 0; ni < 4; ++ni) acc[mi][ni] = ZERO;

#pragma unroll
  for (int j = 0; j < 2; ++j) {
    const int chunk = wave * 2 + j;
    const int row = chunk * 16 + srow;
    async16(Ax + (size_t)(t0 + row) * C_ + scol, &sA[0][chunk * 512]);
    async16(W1 + (size_t)(o0 + row) * C_ + scol, &sB[0][chunk * 512]);
  }

  for (int i = 0; i < 24; ++i) {
    const int buf = i & 1;
    __syncthreads();
    if (i < 23) {
      const int k0 = (i + 1) * 32;
#pragma unroll
      for (int j = 0; j < 2; ++j) {
        const int chunk = wave * 2 + j;
        const int row = chunk * 16 + srow;
        async16(Ax + (size_t)(t0 + row) * C_ + k0 + scol, &sA[buf ^ 1][chunk * 512]);
        async16(W1 + (size_t)(o0 + row) * C_ + k0 + scol, &sB[buf ^ 1][chunk * 512]);
      }
    }

    bf16x8 aF[4], bF[4];
#pragma unroll
    for (int mi = 0; mi < 4; ++mi)
      aF[mi] = *(const bf16x8*)(&sA[buf][(tw * 64 + mi * 16 + ln) * 32 + q * 8]);
#pragma unroll
    for (int ni = 0; ni < 4; ++ni)
      bF[ni] = *(const bf16x8*)(&sB[buf][(ow * 64 + ni * 16 + ln) * 32 + q * 8]);
#pragma unroll
    for (int mi = 0; mi < 4; ++mi)
#pragma unroll
      for (int ni = 0; ni < 4; ++ni)
        acc[mi][ni] = __builtin_amdgcn_mfma_f32_16x16x32_bf16(aF[mi], bF[ni], acc[mi][ni], 0, 0, 0);
  }

  const float QSCL = 0.125f * 1.44269504f;
#pragma unroll
  for (int ni = 0; ni < 4; ++ni) {
    const int o = o0 + ow * 64 + ni * 16 + ln;
    const float bias = bqkv[o];
    const int which = o / C_;          // uniform per block (768 % 128 == 0)
    const int rem = o - which * C_;
    const int bh = b * H_ + (rem >> 6);
    const int dd = rem & 63;
#pragma unroll
    for (int mi = 0; mi < 4; ++mi) {
      const int tb = t0 + tw * 64 + mi * 16 + q * 4;
      f32x4 v = acc[mi][ni];
      if (which == 0) {
#pragma unroll
        for (int r = 0; r < 4; ++r)
          Qb[((size_t)bh * T_ + tb + r) * D_ + dd] = f2bf((v[r] + bias) * QSCL);
      } else if (which == 1) {
#pragma unroll
        for (int r = 0; r < 4; ++r) {
          const int s = tb + r;
          const int cp = (dd >> 3) ^ (s & 7);
          Kb[((size_t)bh * T_ + s) * 64 + (cp << 3) + (dd & 7)] = f2bf(v[r] + bias);
        }
      } else {
        const int tile = tb >> 6, si = tb & 63;
        const int cp = (si >> 3) ^ (dd & 7);
        ushort4 pk;                      // V stored as f16 for the f16 PV MFMA
        pk.x = f2h(v[0] + bias);
        pk.y = f2h(v[1] + bias);
        pk.z = f2h(v[2] + bias);
        pk.w = f2h(v[3] + bias);
        *(ushort4*)(Vb + (((size_t)bh * 32 + tile) * 64 + dd) * 64 + (cp << 3) + (si & 7)) = pk;
      }
    }
  }
}

// ---------------------------------------------------------------- attention
// Fixed-max flash, register-resident P. One block = (bh, 128 t); 4 waves in a
// 2x2 split: wave(si,wj) = t-half wj (64 t) x s-half si (32 s of the 64-s
// tile). QK^T C-layout (s=4q+r, t=ln) == A-layout of 16x16x16 f16 MFMA
// (k=4q+j, m=ln) -> P feeds PV directly from registers (no LDS round-trip).
// K/V double-buffered, 1 barrier/iter; si-combine once at the end via LDS.
__global__ __launch_bounds__(256, 3)
void attn(const unsigned short* __restrict__ Qb,
          const unsigned short* __restrict__ Kb,
          const unsigned short* __restrict__ Vb,
          const float* __restrict__ mbias,
          unsigned short* __restrict__ Ob) {
  __shared__ __align__(16) char smem[32768];
  unsigned short* sK0 = (unsigned short*)smem;             // dbuf 2 x 8KB
  unsigned short* sV0 = (unsigned short*)(smem + 16384);   // dbuf 2 x 8KB

  const int id = blockIdx.x;                  // id = bh + 48*tblk -> XCD = bh%8
  const int bh = id % 48;
  const int tblk = id / 48;                   // 0..15, 128 t each
  const int b = bh / H_, h = bh % H_;
  const int tid = threadIdx.x, wave = tid >> 6, lane = tid & 63;
  const int q = lane >> 4, ln = lane & 15;
  const int wj = wave & 1, si = wave >> 1;    // t-half, s-half
  const int t0w = tblk * 128 + wj * 64;

  // Q fragments (B-operand of QK): [tt][kk], t = t0w + tt*16 + ln
  bf16x8 Qa[4][2];
#pragma unroll
  for (int tt = 0; tt < 4; ++tt) {
    const unsigned short* qrow = Qb + ((size_t)bh * T_ + t0w + tt * 16 + ln) * D_;
    Qa[tt][0] = *(const bf16x8*)(qrow + q * 8);
    Qa[tt][1] = *(const bf16x8*)(qrow + 32 + q * 8);
  }

  const f32x4 ZERO = {0.f, 0.f, 0.f, 0.f};
  f32x4 Oacc[4][4];            // [tt][dt]: O[t=tt*16+4q+r][d=dt*16+ln] partial
  float lac[4] = {0.f, 0.f, 0.f, 0.f};
#pragma unroll
  for (int tt = 0; tt < 4; ++tt)
#pragma unroll
    for (int dt = 0; dt < 4; ++dt) Oacc[tt][dt] = ZERO;

  const unsigned short* gK = Kb + (size_t)bh * T_ * 64;
  const unsigned short* gV = Vb + (size_t)bh * 32 * 4096;

  // prologue: stage iter 0 into buf 0 (K,V: 8 chunks of 1KB, 2 per wave)
#pragma unroll
  for (int j = 0; j < 2; ++j) {
    const int chunk = wave * 2 + j;
    async16(gK + chunk * 512 + lane * 8, sK0 + chunk * 512);
    async16(gV + chunk * 512 + lane * 8, sV0 + chunk * 512);
  }

  for (int it = 0; it < 32; ++it) {
    const int buf = it & 1;
    __syncthreads();                    // vmcnt drain: buf ready & visible
    if (it < 31) {
      const unsigned short* k = gK + (it + 1) * 4096;
      const unsigned short* v = gV + (it + 1) * 4096;
      unsigned short* dK = sK0 + (buf ^ 1) * 4096;
      unsigned short* dV = sV0 + (buf ^ 1) * 4096;
#pragma unroll
      for (int j = 0; j < 2; ++j) {
        const int chunk = wave * 2 + j;
        async16(k + chunk * 512 + lane * 8, dK + chunk * 512);
        async16(v + chunk * 512 + lane * 8, dV + chunk * 512);
      }
    }

    const int s0 = it * 64;
    const float bvl = mbias[b * T_ + s0 + lane];
    const bool anymask = (__ballot(bvl != 0.0f) != 0ull);
    const unsigned short* sKc = sK0 + buf * 4096;
    const unsigned short* sVc = sV0 + buf * 4096;

    // K A-fragments for this wave's 32-s slice (rows si*32 + sb*16 + ln)
    bf16x8 kf[2][2];
#pragma unroll
    for (int sb = 0; sb < 2; ++sb) {
      const unsigned short* krow = sKc + (si * 32 + sb * 16 + ln) * 64;
      kf[sb][0] = *(const bf16x8*)(krow + ((q ^ (ln & 7)) << 3));
      kf[sb][1] = *(const bf16x8*)(krow + (((4 + q) ^ (ln & 7)) << 3));
    }

    f32x4 bb0 = ZERO, bb1 = ZERO;
    if (anymask) {
      bb0 = *(const f32x4*)(mbias + b * T_ + s0 + si * 32 + q * 4);
      bb1 = *(const f32x4*)(mbias + b * T_ + s0 + si * 32 + 16 + q * 4);
    }

    // QK^T -> p = exp2(sc); P stays in registers as f16 A-frags [tt][kh]
    f16x4 Pf[4][2];
#pragma unroll
    for (int tt = 0; tt < 4; ++tt) {
#pragma unroll
      for (int sb = 0; sb < 2; ++sb) {
        f32x4 p0 = __builtin_amdgcn_mfma_f32_16x16x32_bf16(kf[sb][0], Qa[tt][0], ZERO, 0, 0, 0);
        f32x4 sc = __builtin_amdgcn_mfma_f32_16x16x32_bf16(kf[sb][1], Qa[tt][1], p0, 0, 0, 0);
        if (anymask) {
          f32x4 bb = sb ? bb1 : bb0;
#pragma unroll
          for (int r = 0; r < 4; ++r) sc[r] += bb[r];
        }
        float e0 = fexp2(sc[0]), e1 = fexp2(sc[1]);
        float e2 = fexp2(sc[2]), e3 = fexp2(sc[3]);
        lac[tt] += (e0 + e1) + (e2 + e3);
        union { h16x2 h2[2]; f16x4 h4; } u;
        u.h2[0] = __builtin_amdgcn_cvt_pkrtz(e0, e1);
        u.h2[1] = __builtin_amdgcn_cvt_pkrtz(e2, e3);
        Pf[tt][sb] = u.h4;
      }
    }

    // PV: O[t][d] += P (A, registers) x V (B, f16 b64 LDS reads), 2 k-halves
#pragma unroll
    for (int kh = 0; kh < 2; ++kh) {
      f16x4 vf[4];
#pragma unroll
      for (int dt = 0; dt < 4; ++dt)
        vf[dt] = *(const f16x4*)(sVc + (dt * 16 + ln) * 64 +
                                 (((si * 4 + kh * 2 + (q >> 1)) ^ (ln & 7)) << 3) +
                                 ((q & 1) << 2));
#pragma unroll
      for (int tt = 0; tt < 4; ++tt)
#pragma unroll
        for (int dt = 0; dt < 4; ++dt)
          Oacc[tt][dt] = __builtin_amdgcn_mfma_f32_16x16x16f16(Pf[tt][kh], vf[dt], Oacc[tt][dt], 0, 0, 0);
    }
  }

  // reduce l over the 4 quads (lanes sharing ln hold same t)
#pragma unroll
  for (int tt = 0; tt < 4; ++tt) {
    lac[tt] += __shfl_xor(lac[tt], 16, 64);
    lac[tt] += __shfl_xor(lac[tt], 32, 64);
  }

  // ---- si-combine (si=1 -> LDS f16 partials; si=0 merges, normalizes, stores)
  __syncthreads();
  unsigned short* hbuf = (unsigned short*)smem;       // [wj][64t][64d] f16
  float* lbuf = (float*)(smem + 16384);               // [wj][64t] f32
  if (si == 1) {
#pragma unroll
    for (int tt = 0; tt < 4; ++tt) {
#pragma unroll
      for (int dt = 0; dt < 4; ++dt)
#pragma unroll
        for (int r = 0; r < 4; ++r)
          hbuf[wj * 4096 + (tt * 16 + q * 4 + r) * 64 + dt * 16 + ln] = f2h(Oacc[tt][dt][r]);
      if (q == 0) lbuf[wj * 64 + tt * 16 + ln] = lac[tt];
    }
  }
  __syncthreads();
  if (si == 0) {
#pragma unroll
    for (int tt = 0; tt < 4; ++tt) {
      float inv[4];
#pragma unroll
      for (int r = 0; r < 4; ++r) {
        const int tl = tt * 16 + q * 4 + r;
        float l = __shfl(lac[tt], q * 4 + r, 64);   // lane (0, 4q+r) holds t=tl
        l += lbuf[wj * 64 + tl];
        inv[r] = 1.0f / l;
      }
#pragma unroll
      for (int dt = 0; dt < 4; ++dt) {
#pragma unroll
        for (int r = 0; r < 4; ++r) {
          const int tl = tt * 16 + q * 4 + r;
          const int dl = dt * 16 + ln;
          float o = Oacc[tt][dt][r] + h2f(hbuf[wj * 4096 + tl * 64 + dl]);
          Ob[((size_t)b * T_ + t0w + tl) * C_ + h * D_ + dl] = f2bf(o * inv[r]);
        }
      }
    }
  }
}

// ---------------------------------------------------------------- out GEMM
__global__ __launch_bounds__(256)
void gemm_out(const unsigned short* __restrict__ Ob,
              const unsigned short* __restrict__ W2,
              const float* __restrict__ bout,
              float* __restrict__ out) {
  __shared__ unsigned short sA[2][128 * 32];
  __shared__ unsigned short sB[2][128 * 32];

  const int b   = blockIdx.z;
  const int o0  = blockIdx.y * 128;
  const int t0  = blockIdx.x * 128;
  const int tid = threadIdx.x;
  const int wave = tid >> 6, lane = tid & 63;
  const int q = lane >> 4, ln = lane & 15;
  const int tw = wave >> 1, ow = wave & 1;

  const unsigned short* Bo = Ob + (size_t)b * T_ * C_;
  const int srow = lane >> 2;
  const int scol = (lane & 3) * 8;

  const f32x4 ZERO = {0.f, 0.f, 0.f, 0.f};
  f32x4 acc[4][4];
#pragma unroll
  for (int mi = 0; mi < 4; ++mi)
#pragma unroll
    for (int ni = 0; ni < 4; ++ni) acc[mi][ni] = ZERO;

#pragma unroll
  for (int j = 0; j < 2; ++j) {
    const int chunk = wave * 2 + j;
    const int row = chunk * 16 + srow;
    async16(W2 + (size_t)(o0 + row) * C_ + scol, &sA[0][chunk * 512]);
    async16(Bo + (size_t)(t0 + row) * C_ + scol, &sB[0][chunk * 512]);
  }

  for (int i = 0; i < 24; ++i) {
    const int buf = i & 1;
    __syncthreads();
    if (i < 23) {
      const int k0 = (i + 1) * 32;
#pragma unroll
      for (int j = 0; j < 2; ++j) {
        const int chunk = wave * 2 + j;
        const int row = chunk * 16 + srow;
        async16(W2 + (size_t)(o0 + row) * C_ + k0 + scol, &sA[buf ^ 1][chunk * 512]);
        async16(Bo + (size_t)(t0 + row) * C_ + k0 + scol, &sB[buf ^ 1][chunk * 512]);
      }
    }

    bf16x8 aF[4], bF[4];
#pragma unroll
    for (int mi = 0; mi < 4; ++mi)
      aF[mi] = *(const bf16x8*)(&sA[buf][(tw * 64 + mi * 16 + ln) * 32 + q * 8]);
#pragma unroll
    for (int ni = 0; ni < 4; ++ni)
      bF[ni] = *(const bf16x8*)(&sB[buf][(ow * 64 + ni * 16 + ln) * 32 + q * 8]);
#pragma unroll
    for (int mi = 0; mi < 4; ++mi)
#pragma unroll
      for (int ni = 0; ni < 4; ++ni)
        acc[mi][ni] = __builtin_amdgcn_mfma_f32_16x16x32_bf16(aF[mi], bF[ni], acc[mi][ni], 0, 0, 0);
  }

#pragma unroll
  for (int mi = 0; mi < 4; ++mi) {
    const int ob = o0 + tw * 64 + mi * 16 + q * 4;
#pragma unroll
    for (int ni = 0; ni < 4; ++ni) {
      const int t = t0 + ow * 64 + ni * 16 + ln;
      f32x4 v = acc[mi][ni];
#pragma unroll
      for (int r = 0; r < 4; ++r)
        out[((size_t)b * C_ + ob + r) * T_ + t] = v[r] + bout[ob + r];
    }
  }
}

// ---------------------------------------------------------------- launch

extern "C" void kernel_launch(void* const* d_in, const int* in_sizes, int n_in,
                              void* d_out, int out_size, void* d_ws, size_t ws_size,
                              hipStream_t stream) {
  (void)in_sizes; (void)n_in; (void)out_size; (void)ws_size;
  const float* x    = (const float*)d_in[0];
  const int*   mask = (const int*)d_in[1];
  const float* Wqkv = (const float*)d_in[2];
  const float* bqkv = (const float*)d_in[3];
  const float* Wout = (const float*)d_in[4];
  const float* bout = (const float*)d_in[5];
  float* out = (float*)d_out;

  const size_t szHead = (size_t)B_ * H_ * T_ * D_;   // 6291456 elems
  const size_t szBTC  = (size_t)B_ * T_ * C_;        // 6291456 elems
  unsigned short* Qb  = (unsigned short*)d_ws;
  unsigned short* Kb  = Qb + szHead;
  unsigned short* Vb  = Kb + szHead;
  unsigned short* Ob  = Vb + szHead;
  unsigned short* xT  = Ob + szBTC;
  unsigned short* W1b = xT + szBTC;
  unsigned short* W2b = W1b + (size_t)O3_ * C_;
  float* mbias        = (float*)(W2b + (size_t)C_ * C_);

  cvt_f32_bf16<<<dim3((O3_ * C_ / 4 + 255) / 256), 256, 0, stream>>>(Wqkv, W1b, O3_ * C_ / 4);
  cvt_f32_bf16<<<dim3((C_ * C_ / 4 + 255) / 256), 256, 0, stream>>>(Wout, W2b, C_ * C_ / 4);
  make_bias<<<dim3((B_ * T_ + 255) / 256), 256, 0, stream>>>(mask, mbias, B_ * T_);
  transpose_x<<<dim3(T_ / 32, C_ / 32, B_), 256, 0, stream>>>(x, xT);
  gemm_qkv<<<dim3(T_ / 128, O3_ / 128, B_), 256, 0, stream>>>(xT, W1b, bqkv, Qb, Kb, Vb);
  attn<<<dim3(768), 256, 0, stream>>>(Qb, Kb, Vb, mbias, Ob);
  gemm_out<<<dim3(T_ / 128, C_ / 128, B_), 256, 0, stream>>>(Ob, W2b, bout, out);
}